// Round 4
// baseline (1600.145 us; speedup 1.0000x reference)
//
#include <hip/hip_runtime.h>

#define N_NODES 50000
#define N_EDGES 1600000

typedef _Float16 f16x8 __attribute__((ext_vector_type(8)));
typedef float f32x4 __attribute__((ext_vector_type(4)));

__device__ __forceinline__ float fast_rcp(float v) {
#if __has_builtin(__builtin_amdgcn_rcpf)
    return __builtin_amdgcn_rcpf(v);
#else
    return __frcp_rn(v);
#endif
}

// ---------------------------------------------------------------------------
// prep_weights: f16 weight images, transposed ([n][k]) and 16B-chunk
// XOR-swizzled (chunk' = chunk ^ (n&7)).
// W1img: [128 n][64 k] (Wf1 50x128, K zero-padded to 64).  W2img: [128][128].
// ---------------------------------------------------------------------------
__global__ void prep_weights(const float* __restrict__ Wf1,
                             const float* __restrict__ Wf2,
                             _Float16* __restrict__ W1img,
                             _Float16* __restrict__ W2img) {
    int i = blockIdx.x * 256 + threadIdx.x;
    if (i < 8192) {
        int n = i >> 6, k = i & 63;
        float v = (k < 50) ? Wf1[k * 128 + n] : 0.0f;
        W1img[n * 64 + (((k >> 3) ^ (n & 7)) << 3) + (k & 7)] = (_Float16)v;
    }
    if (i < 16384) {
        int n = i >> 7, k = i & 127;
        W2img[n * 128 + (((k >> 3) ^ (n & 7)) << 3) + (k & 7)] =
            (_Float16)Wf2[k * 128 + n];
    }
}

// ---------------------------------------------------------------------------
// Counting sort by dst: hist -> 3-kernel shuffle scan -> scatter (eid only).
// ---------------------------------------------------------------------------
__global__ void hist_kernel(const int* __restrict__ dstv, int* __restrict__ cnt) {
    int e = blockIdx.x * 256 + threadIdx.x;
    if (e < N_EDGES) atomicAdd(&cnt[dstv[e]], 1);
}

__global__ __launch_bounds__(1024) void scan_reduce(const int* __restrict__ cnt,
                                                    int* __restrict__ bsum) {
    __shared__ int ws[16];
    int tid = threadIdx.x, lane = tid & 63;
    int i = blockIdx.x * 1024 + tid;
    int x = (i < N_NODES) ? cnt[i] : 0;
    for (int o = 32; o > 0; o >>= 1) x += __shfl_down(x, o);
    if (lane == 0) ws[tid >> 6] = x;
    __syncthreads();
    if (tid == 0) {
        int s = 0;
        for (int w = 0; w < 16; ++w) s += ws[w];
        bsum[blockIdx.x] = s;
    }
}

__global__ void scan_top(int* __restrict__ bsum) {   // 49 block sums, serial
    if (threadIdx.x == 0) {
        int s = 0;
        for (int b = 0; b < 49; ++b) { int v = bsum[b]; bsum[b] = s; s += v; }
    }
}

__global__ __launch_bounds__(1024) void scan_apply(int* __restrict__ cnt,
                                                   const int* __restrict__ bsum) {
    __shared__ int ws[16], wo[16];
    int tid = threadIdx.x, lane = tid & 63, wid = tid >> 6;
    int i = blockIdx.x * 1024 + tid;
    int x = (i < N_NODES) ? cnt[i] : 0;
    int incl = x;
    for (int o = 1; o < 64; o <<= 1) {
        int y = __shfl_up(incl, o);
        if (lane >= o) incl += y;
    }
    if (lane == 63) ws[wid] = incl;
    __syncthreads();
    if (tid == 0) {
        int s = 0;
        for (int w = 0; w < 16; ++w) { wo[w] = s; s += ws[w]; }
    }
    __syncthreads();
    if (i < N_NODES) cnt[i] = bsum[blockIdx.x] + wo[wid] + incl - x;  // exclusive
}

__global__ void scatter_kernel(const int* __restrict__ dstv,
                               int* __restrict__ cursor,
                               int* __restrict__ eids) {
    int e = blockIdx.x * 256 + threadIdx.x;
    if (e < N_EDGES) {
        int d = dstv[e];
        int pos = atomicAdd(&cursor[d], 1);
        eids[pos] = e;          // 4B payload; src/dst/rij gathered by eid later
    }
}

// ---------------------------------------------------------------------------
// hv_kernel (fp32 compute, f16 store): hv = feat @ W_in2f.
// ---------------------------------------------------------------------------
__global__ __launch_bounds__(256) void hv_kernel(const float* __restrict__ feat,
                                                 const float* __restrict__ W,
                                                 _Float16* __restrict__ hvh) {
    __shared__ float sAT[128 * 20];
    const int tid = threadIdx.x;
    const int row0 = blockIdx.x * 16;
    for (int t = 0; t < 8; ++t) {
        int flat = tid + 256 * t;
        int rr = flat >> 7, k = flat & 127;
        sAT[k * 20 + rr] = feat[(row0 + rr) * 128 + k];
    }
    __syncthreads();
    const int c = tid & 127, rh = tid >> 7;
    float acc[8] = {0, 0, 0, 0, 0, 0, 0, 0};
    for (int k = 0; k < 128; ++k) {
        float wval = W[k * 128 + c];
        const float4 alo = *(const float4*)&sAT[k * 20 + rh * 8];
        const float4 ahi = *(const float4*)&sAT[k * 20 + rh * 8 + 4];
        acc[0] += alo.x * wval; acc[1] += alo.y * wval;
        acc[2] += alo.z * wval; acc[3] += alo.w * wval;
        acc[4] += ahi.x * wval; acc[5] += ahi.y * wval;
        acc[6] += ahi.z * wval; acc[7] += ahi.w * wval;
    }
    for (int r = 0; r < 8; ++r)
        hvh[(row0 + rh * 8 + r) * 128 + c] = (_Float16)acc[r];
}

// ---------------------------------------------------------------------------
// edge_kernel, 512 threads (8 waves x 16 rows), dst-sorted edges.
// MULTI-TILE: grid 2500, 5 tiles of 128 edges per block. sW2 stays resident;
// sW1 re-staged per tile (L1-hot); next-tile eids/fij/hv-prefetch issued
// under current tile's compute so VMEM latency never drains cold.
// LDS: R0[0,16K): sW1 during GEMM1, then sX rows 0-63; R1[16K,48K): sW2
//      resident; R2[48K,64K): sX rows 64-127. sX = sT (GEMM2 input) then
//      sM (he, overwritten in place), stride 128, 16B-chunk XOR swizzle.
// MFMA 16x16x32_f16 layouts (verified): A: m=lane&15, k=(lane>>4)*8+j;
//   D: row=(lane>>4)*4+r, col=lane&15.
// ---------------------------------------------------------------------------
__global__ __launch_bounds__(512, 4) void edge_kernel(
        const float* __restrict__ fij, const _Float16* __restrict__ hvh,
        const _Float16* __restrict__ W1img, const _Float16* __restrict__ W2img,
        const float* __restrict__ bf1, const float* __restrict__ bf2,
        const int* __restrict__ eids, const int* __restrict__ srcv,
        const int* __restrict__ dstv, const float* __restrict__ rij,
        float* __restrict__ agg) {
    __shared__ __align__(16) char smem[65536];
    __shared__ __align__(16) int4 sMeta[2][128];
    _Float16* sW1 = (_Float16*)smem;              // [128][64]   per-tile
    _Float16* sW2 = (_Float16*)(smem + 16384);    // [128][128]  resident
    _Float16* sX0 = (_Float16*)smem;              // sX rows 0-63
    _Float16* sX1 = (_Float16*)(smem + 49152);    // sX rows 64-127

    const int tid = threadIdx.x;
    const int lane = tid & 63;
    const int wv = tid >> 6;          // 0..7 -> rows [wv*16, wv*16+16)
    const int l15 = lane & 15;
    const int q = lane >> 4;
    const int col2 = tid & 63;        // reduction col-pair
    const int rseg0 = wv * 16;        // reduction rows
    const int arow = wv * 16 + l15;   // this lane's A-frag row

    long e0 = (long)blockIdx.x * 640;

    // ---- afrag(0): direct global->reg fij loads ----
    const int kb = 32 + q * 8;
    const float2 z2 = make_float2(0.f, 0.f);
    int eid = eids[e0 + arow];
    const float* frow = fij + (long)eid * 50;
    float2 p0 = *(const float2*)(frow + q * 8 + 0);
    float2 p1 = *(const float2*)(frow + q * 8 + 2);
    float2 p2 = *(const float2*)(frow + q * 8 + 4);
    float2 p3 = *(const float2*)(frow + q * 8 + 6);
    float2 p4 = (kb + 1 < 50) ? *(const float2*)(frow + kb + 0) : z2;
    float2 p5 = (kb + 3 < 50) ? *(const float2*)(frow + kb + 2) : z2;
    float2 p6 = (kb + 5 < 50) ? *(const float2*)(frow + kb + 4) : z2;
    float2 p7 = (kb + 7 < 50) ? *(const float2*)(frow + kb + 6) : z2;

    // ---- stage sMeta[0] (gather by eid) + weight images ----
    if (tid < 128) {
        int e = eids[e0 + tid];
        sMeta[0][tid] = make_int4(e, srcv[e], dstv[e], __float_as_int(rij[e]));
    }
    const float4* g1 = (const float4*)W1img;   // 1024 f4
    const float4* g2 = (const float4*)W2img;   // 2048 f4
    float4* d1 = (float4*)sW1;
    float4* d2 = (float4*)sW2;
    d1[tid] = g1[tid]; d1[tid + 512] = g1[tid + 512];
    for (int u = 0; u < 4; ++u) d2[tid + 512 * u] = g2[tid + 512 * u];
    float b1v[8], b2v[8];
    for (int nb = 0; nb < 8; ++nb) {
        b1v[nb] = bf1[nb * 16 + l15];
        b2v[nb] = bf2[nb * 16 + l15];
    }
    f16x8 a0, a1;
    a0[0] = (_Float16)p0.x; a0[1] = (_Float16)p0.y;
    a0[2] = (_Float16)p1.x; a0[3] = (_Float16)p1.y;
    a0[4] = (_Float16)p2.x; a0[5] = (_Float16)p2.y;
    a0[6] = (_Float16)p3.x; a0[7] = (_Float16)p3.y;
    a1[0] = (_Float16)p4.x; a1[1] = (_Float16)p4.y;
    a1[2] = (_Float16)p5.x; a1[3] = (_Float16)p5.y;
    a1[4] = (_Float16)p6.x; a1[5] = (_Float16)p6.y;
    a1[6] = (_Float16)p7.x; a1[7] = (_Float16)p7.y;
    __syncthreads();

    // ---- pf(0): hv gather for tile-0 reduction ----
    unsigned int pf[16];
    #pragma unroll
    for (int i = 0; i < 16; ++i) {
        long srcn = sMeta[0][rseg0 + i].y;         // wave-uniform broadcast
        pf[i] = *(const unsigned int*)(hvh + srcn * 128 + col2 * 2);
    }

    for (int t = 0; t < 5; ++t) {
        const int4* sMc = sMeta[t & 1];
        int4* sMn = sMeta[(t + 1) & 1];
        const bool more = (t < 4);
        const long e0n = e0 + 128;

        // ---- GEMM1: [16 x 64] x [64 x 128] per wave, A from regs ----
        f32x4 acc[8];
        for (int nb = 0; nb < 8; ++nb) acc[nb] = (f32x4){0.f, 0.f, 0.f, 0.f};
        {
            f16x8 b[8];
            for (int nb = 0; nb < 8; ++nb) {
                int n = nb * 16 + l15;
                b[nb] = *(const f16x8*)&sW1[n * 64 + ((q ^ (n & 7)) << 3)];
            }
            for (int nb = 0; nb < 8; ++nb)
                acc[nb] = __builtin_amdgcn_mfma_f32_16x16x32_f16(a0, b[nb], acc[nb], 0, 0, 0);
            for (int nb = 0; nb < 8; ++nb) {
                int n = nb * 16 + l15;
                b[nb] = *(const f16x8*)&sW1[n * 64 + (((4 + q) ^ (n & 7)) << 3)];
            }
            for (int nb = 0; nb < 8; ++nb)
                acc[nb] = __builtin_amdgcn_mfma_f32_16x16x32_f16(a1, b[nb], acc[nb], 0, 0, 0);
        }
        __syncthreads();   // A: sW1 dead -> sX writable

        // ---- next-tile meta gathers (issue early, land under GEMM2) ----
        int4 mN = make_int4(0, 0, 0, 0);
        int eidN = 0;
        if (more) {
            if (tid < 128) {
                int e = eids[e0n + tid];
                mN = make_int4(e, srcv[e], dstv[e], __float_as_int(rij[e]));
            }
            eidN = eids[e0n + arow];
        }

        // ---- epilogue1: t = swish(x1 + bf1) -> sX (swizzled) ----
        #pragma unroll
        for (int nb = 0; nb < 8; ++nb)
            #pragma unroll
            for (int r = 0; r < 4; ++r) {
                float x = acc[nb][r] + b1v[nb];
                float tt = x * fast_rcp(1.0f + __expf(-x));
                int row = wv * 16 + q * 4 + r;
                int col = nb * 16 + l15;
                _Float16* base = (row < 64) ? sX0 + row * 128 : sX1 + (row - 64) * 128;
                base[(((col >> 3) ^ (row & 7)) << 3) + (col & 7)] = (_Float16)tt;
            }
        // next-tile fij loads (dependent on eidN; land during GEMM2)
        float2 n0, n1, n2, n3, n4, n5, n6, n7;
        if (more) {
            const float* frn = fij + (long)eidN * 50;
            n0 = *(const float2*)(frn + q * 8 + 0);
            n1 = *(const float2*)(frn + q * 8 + 2);
            n2 = *(const float2*)(frn + q * 8 + 4);
            n3 = *(const float2*)(frn + q * 8 + 6);
            n4 = (kb + 1 < 50) ? *(const float2*)(frn + kb + 0) : z2;
            n5 = (kb + 3 < 50) ? *(const float2*)(frn + kb + 2) : z2;
            n6 = (kb + 5 < 50) ? *(const float2*)(frn + kb + 4) : z2;
            n7 = (kb + 7 < 50) ? *(const float2*)(frn + kb + 6) : z2;
        }
        __syncthreads();   // B: sX(sT) ready

        if (more && tid < 128) sMn[tid] = mN;   // ds_write during GEMM2 phase

        // ---- GEMM2: [16 x 128] x [128 x 128] per wave ----
        for (int nb = 0; nb < 8; ++nb) acc[nb] = (f32x4){0.f, 0.f, 0.f, 0.f};
        {
            const int row = wv * 16 + l15;
            const _Float16* abase = (row < 64) ? sX0 + row * 128 : sX1 + (row - 64) * 128;
            for (int ks = 0; ks < 4; ++ks) {
                int c = ks * 4 + q;
                f16x8 a = *(const f16x8*)&abase[(c ^ (row & 7)) << 3];
                for (int nb = 0; nb < 8; ++nb) {
                    int n = nb * 16 + l15;
                    f16x8 b = *(const f16x8*)&sW2[n * 128 + ((c ^ (n & 7)) << 3)];
                    acc[nb] = __builtin_amdgcn_mfma_f32_16x16x32_f16(a, b, acc[nb], 0, 0, 0);
                }
            }
        }
        __syncthreads();   // C: sX(sT) dead; sMeta[next] visible

        // ---- epilogue2: he = (x2+bf2)*C -> sX overwrite (same swizzle) ----
        #pragma unroll
        for (int r = 0; r < 4; ++r) {
            int row = wv * 16 + q * 4 + r;
            float rv = __int_as_float(sMc[row].w);
            float Cr = (rv < 5.0f) ? 0.5f * (__cosf(0.6283185307179586f * rv) + 1.0f) : 0.0f;
            #pragma unroll
            for (int nb = 0; nb < 8; ++nb) {
                int col = nb * 16 + l15;
                _Float16* base = (row < 64) ? sX0 + row * 128 : sX1 + (row - 64) * 128;
                base[(((col >> 3) ^ (row & 7)) << 3) + (col & 7)] =
                    (_Float16)((acc[nb][r] + b2v[nb]) * Cr);
            }
        }
        // ---- next-tile: cvt afrag, pf gathers, sW1 restage loads ----
        f16x8 a0n, a1n;
        unsigned int pfN[16];
        float4 w1a, w1b;
        if (more) {
            a0n[0] = (_Float16)n0.x; a0n[1] = (_Float16)n0.y;
            a0n[2] = (_Float16)n1.x; a0n[3] = (_Float16)n1.y;
            a0n[4] = (_Float16)n2.x; a0n[5] = (_Float16)n2.y;
            a0n[6] = (_Float16)n3.x; a0n[7] = (_Float16)n3.y;
            a1n[0] = (_Float16)n4.x; a1n[1] = (_Float16)n4.y;
            a1n[2] = (_Float16)n5.x; a1n[3] = (_Float16)n5.y;
            a1n[4] = (_Float16)n6.x; a1n[5] = (_Float16)n6.y;
            a1n[6] = (_Float16)n7.x; a1n[7] = (_Float16)n7.y;
            #pragma unroll
            for (int i = 0; i < 16; ++i) {
                long srcn = sMn[rseg0 + i].y;
                pfN[i] = *(const unsigned int*)(hvh + srcn * 128 + col2 * 2);
            }
            w1a = g1[tid]; w1b = g1[tid + 512];   // L1-hot
        }
        __syncthreads();   // D: sX(sM) ready

        // ---- reduction: 8 segs x 16 rows x 64 col-pairs ----
        {
            const _Float16* rb = (rseg0 < 64) ? sX0 + rseg0 * 128
                                              : sX1 + (rseg0 - 64) * 128;
            float run0 = 0.0f, run1 = 0.0f;
            int cur = sMc[rseg0].z;
            #pragma unroll
            for (int i = 0; i < 16; ++i) {
                int d = sMc[rseg0 + i].z;           // wave-uniform broadcast
                if (d != cur) {                     // wave-uniform branch
                    atomicAdd(&agg[(long)cur * 128 + col2 * 2], run0);
                    atomicAdd(&agg[(long)cur * 128 + col2 * 2 + 1], run1);
                    run0 = 0.0f; run1 = 0.0f; cur = d;
                }
                union { unsigned int u; _Float16 h[2]; } hv2; hv2.u = pf[i];
                union { unsigned int u; _Float16 h[2]; } m2;
                m2.u = *(const unsigned int*)
                    &rb[i * 128 + ((((col2 >> 2) ^ (i & 7)) << 3) | ((col2 & 3) << 1))];
                run0 += (float)hv2.h[0] * (float)m2.h[0];
                run1 += (float)hv2.h[1] * (float)m2.h[1];
            }
            atomicAdd(&agg[(long)cur * 128 + col2 * 2], run0);
            atomicAdd(&agg[(long)cur * 128 + col2 * 2 + 1], run1);
        }

        if (more) {
            __syncthreads();   // E: sX dead -> R0 free for sW1
            d1[tid] = w1a; d1[tid + 512] = w1b;
            a0 = a0n; a1 = a1n;
            #pragma unroll
            for (int i = 0; i < 16; ++i) pf[i] = pfN[i];
            e0 = e0n;
            __syncthreads();   // F: sW1 ready for GEMM1(t+1)
        }
    }
}

// ---------------------------------------------------------------------------
// out_kernel (fp32): out = swish(agg @ Wm1 + bm1) @ Wm2 + bm2, fused.
// ---------------------------------------------------------------------------
__global__ __launch_bounds__(256) void out_kernel(const float* __restrict__ agg,
                                                  const float* __restrict__ Wm1,
                                                  const float* __restrict__ bm1,
                                                  const float* __restrict__ Wm2,
                                                  const float* __restrict__ bm2,
                                                  float* __restrict__ out) {
    __shared__ float sAT[128 * 20];
    __shared__ float sTT[128 * 20];
    const int tid = threadIdx.x;
    const int row0 = blockIdx.x * 16;
    for (int t = 0; t < 8; ++t) {
        int flat = tid + 256 * t;
        int rr = flat >> 7, k = flat & 127;
        sAT[k * 20 + rr] = agg[(row0 + rr) * 128 + k];
    }
    __syncthreads();
    const int c = tid & 127, rh = tid >> 7;
    float acc[8] = {0, 0, 0, 0, 0, 0, 0, 0};
    for (int k = 0; k < 128; ++k) {
        float wval = Wm1[k * 128 + c];
        const float4 alo = *(const float4*)&sAT[k * 20 + rh * 8];
        const float4 ahi = *(const float4*)&sAT[k * 20 + rh * 8 + 4];
        acc[0] += alo.x * wval; acc[1] += alo.y * wval;
        acc[2] += alo.z * wval; acc[3] += alo.w * wval;
        acc[4] += ahi.x * wval; acc[5] += ahi.y * wval;
        acc[6] += ahi.z * wval; acc[7] += ahi.w * wval;
    }
    float bm1c = bm1[c];
    for (int r = 0; r < 8; ++r) {
        float x = acc[r] + bm1c;
        sTT[c * 20 + rh * 8 + r] = x * fast_rcp(1.0f + __expf(-x));
    }
    __syncthreads();
    float acc2[8] = {0, 0, 0, 0, 0, 0, 0, 0};
    for (int k = 0; k < 128; ++k) {
        float wval = Wm2[k * 128 + c];
        const float4 alo = *(const float4*)&sTT[k * 20 + rh * 8];
        const float4 ahi = *(const float4*)&sTT[k * 20 + rh * 8 + 4];
        acc2[0] += alo.x * wval; acc2[1] += alo.y * wval;
        acc2[2] += alo.z * wval; acc2[3] += alo.w * wval;
        acc2[4] += ahi.x * wval; acc2[5] += ahi.y * wval;
        acc2[6] += ahi.z * wval; acc2[7] += ahi.w * wval;
    }
    float bm2c = bm2[c];
    for (int r = 0; r < 8; ++r)
        out[(row0 + rh * 8 + r) * 128 + c] = acc2[r] + bm2c;
}

// ---------------------------------------------------------------------------
extern "C" void kernel_launch(void* const* d_in, const int* in_sizes, int n_in,
                              void* d_out, int out_size, void* d_ws, size_t ws_size,
                              hipStream_t stream) {
    const float* feat   = (const float*)d_in[0];
    const float* fij    = (const float*)d_in[1];
    const float* rij    = (const float*)d_in[2];
    const int*   srcv   = (const int*)d_in[3];
    const int*   dstv   = (const int*)d_in[4];
    const float* W_in2f = (const float*)d_in[5];
    const float* Wf1    = (const float*)d_in[6];
    const float* bf1    = (const float*)d_in[7];
    const float* Wf2    = (const float*)d_in[8];
    const float* bf2    = (const float*)d_in[9];
    const float* Wm1    = (const float*)d_in[10];
    const float* bm1    = (const float*)d_in[11];
    const float* Wm2    = (const float*)d_in[12];
    const float* bm2    = (const float*)d_in[13];
    float* out = (float*)d_out;

    char* ws = (char*)d_ws;
    float*    agg   = (float*)ws;                           // 25,600,000 B
    _Float16* hvh   = (_Float16*)(ws + 25600000);           // 12,800,000 B
    int*      eids  = (int*)(ws + 38400000);                //  6,400,000 B
    int*      cnt   = (int*)(ws + 64000000);                //    200,000 B
    int*      bsum  = (int*)(ws + 64200000);                //        256 B
    _Float16* W1img = (_Float16*)(ws + 64200704);           //     16,384 B
    _Float16* W2img = (_Float16*)(ws + 64217088);           //     32,768 B

    hipMemsetAsync(agg, 0, (size_t)N_NODES * 128 * sizeof(float), stream);
    hipMemsetAsync(cnt, 0, (size_t)N_NODES * sizeof(int), stream);
    prep_weights<<<64, 256, 0, stream>>>(Wf1, Wf2, W1img, W2img);
    hv_kernel<<<3125, 256, 0, stream>>>(feat, W_in2f, hvh);
    hist_kernel<<<(N_EDGES + 255) / 256, 256, 0, stream>>>(dstv, cnt);
    scan_reduce<<<49, 1024, 0, stream>>>(cnt, bsum);
    scan_top<<<1, 64, 0, stream>>>(bsum);
    scan_apply<<<49, 1024, 0, stream>>>(cnt, bsum);
    scatter_kernel<<<(N_EDGES + 255) / 256, 256, 0, stream>>>(dstv, cnt, eids);
    edge_kernel<<<2500, 512, 0, stream>>>(fij, hvh, W1img, W2img, bf1, bf2,
                                          eids, srcv, dstv, rij, agg);
    out_kernel<<<3125, 256, 0, stream>>>(agg, Wm1, bm1, Wm2, bm2, out);
}

// Round 5
// 981.479 us; speedup vs baseline: 1.6303x; 1.6303x over previous
//
#include <hip/hip_runtime.h>

#define N_NODES 50000
#define N_EDGES 1600000

typedef _Float16 f16x8 __attribute__((ext_vector_type(8)));
typedef float f32x4 __attribute__((ext_vector_type(4)));

__device__ __forceinline__ float fast_rcp(float v) {
#if __has_builtin(__builtin_amdgcn_rcpf)
    return __builtin_amdgcn_rcpf(v);
#else
    return __frcp_rn(v);
#endif
}

// ---------------------------------------------------------------------------
// prep_weights: f16 weight images, transposed ([n][k]) and 16B-chunk
// XOR-swizzled (chunk' = chunk ^ (n&7)).
// W1img: [128 n][64 k] (Wf1 50x128, K zero-padded to 64).  W2img: [128][128].
// ---------------------------------------------------------------------------
__global__ void prep_weights(const float* __restrict__ Wf1,
                             const float* __restrict__ Wf2,
                             _Float16* __restrict__ W1img,
                             _Float16* __restrict__ W2img) {
    int i = blockIdx.x * 256 + threadIdx.x;
    if (i < 8192) {
        int n = i >> 6, k = i & 63;
        float v = (k < 50) ? Wf1[k * 128 + n] : 0.0f;
        W1img[n * 64 + (((k >> 3) ^ (n & 7)) << 3) + (k & 7)] = (_Float16)v;
    }
    if (i < 16384) {
        int n = i >> 7, k = i & 127;
        W2img[n * 128 + (((k >> 3) ^ (n & 7)) << 3) + (k & 7)] =
            (_Float16)Wf2[k * 128 + n];
    }
}

// ---------------------------------------------------------------------------
// Counting sort by dst: hist -> 3-kernel shuffle scan -> scatter (eid only).
// ---------------------------------------------------------------------------
__global__ void hist_kernel(const int* __restrict__ dstv, int* __restrict__ cnt) {
    int e = blockIdx.x * 256 + threadIdx.x;
    if (e < N_EDGES) atomicAdd(&cnt[dstv[e]], 1);
}

__global__ __launch_bounds__(1024) void scan_reduce(const int* __restrict__ cnt,
                                                    int* __restrict__ bsum) {
    __shared__ int ws[16];
    int tid = threadIdx.x, lane = tid & 63;
    int i = blockIdx.x * 1024 + tid;
    int x = (i < N_NODES) ? cnt[i] : 0;
    for (int o = 32; o > 0; o >>= 1) x += __shfl_down(x, o);
    if (lane == 0) ws[tid >> 6] = x;
    __syncthreads();
    if (tid == 0) {
        int s = 0;
        for (int w = 0; w < 16; ++w) s += ws[w];
        bsum[blockIdx.x] = s;
    }
}

__global__ void scan_top(int* __restrict__ bsum) {   // 49 block sums, serial
    if (threadIdx.x == 0) {
        int s = 0;
        for (int b = 0; b < 49; ++b) { int v = bsum[b]; bsum[b] = s; s += v; }
    }
}

__global__ __launch_bounds__(1024) void scan_apply(int* __restrict__ cnt,
                                                   const int* __restrict__ bsum) {
    __shared__ int ws[16], wo[16];
    int tid = threadIdx.x, lane = tid & 63, wid = tid >> 6;
    int i = blockIdx.x * 1024 + tid;
    int x = (i < N_NODES) ? cnt[i] : 0;
    int incl = x;
    for (int o = 1; o < 64; o <<= 1) {
        int y = __shfl_up(incl, o);
        if (lane >= o) incl += y;
    }
    if (lane == 63) ws[wid] = incl;
    __syncthreads();
    if (tid == 0) {
        int s = 0;
        for (int w = 0; w < 16; ++w) { wo[w] = s; s += ws[w]; }
    }
    __syncthreads();
    if (i < N_NODES) cnt[i] = bsum[blockIdx.x] + wo[wid] + incl - x;  // exclusive
}

__global__ void scatter_kernel(const int* __restrict__ dstv,
                               int* __restrict__ cursor,
                               int* __restrict__ eids) {
    int e = blockIdx.x * 256 + threadIdx.x;
    if (e < N_EDGES) {
        int d = dstv[e];
        int pos = atomicAdd(&cursor[d], 1);
        eids[pos] = e;          // 4B payload; src/dst/rij gathered by eid later
    }
}

// ---------------------------------------------------------------------------
// hv_kernel (fp32 compute, f16 store): hv = feat @ W_in2f.
// ---------------------------------------------------------------------------
__global__ __launch_bounds__(256) void hv_kernel(const float* __restrict__ feat,
                                                 const float* __restrict__ W,
                                                 _Float16* __restrict__ hvh) {
    __shared__ float sAT[128 * 20];
    const int tid = threadIdx.x;
    const int row0 = blockIdx.x * 16;
    for (int t = 0; t < 8; ++t) {
        int flat = tid + 256 * t;
        int rr = flat >> 7, k = flat & 127;
        sAT[k * 20 + rr] = feat[(row0 + rr) * 128 + k];
    }
    __syncthreads();
    const int c = tid & 127, rh = tid >> 7;
    float acc[8] = {0, 0, 0, 0, 0, 0, 0, 0};
    for (int k = 0; k < 128; ++k) {
        float wval = W[k * 128 + c];
        const float4 alo = *(const float4*)&sAT[k * 20 + rh * 8];
        const float4 ahi = *(const float4*)&sAT[k * 20 + rh * 8 + 4];
        acc[0] += alo.x * wval; acc[1] += alo.y * wval;
        acc[2] += alo.z * wval; acc[3] += alo.w * wval;
        acc[4] += ahi.x * wval; acc[5] += ahi.y * wval;
        acc[6] += ahi.z * wval; acc[7] += ahi.w * wval;
    }
    for (int r = 0; r < 8; ++r)
        hvh[(row0 + rh * 8 + r) * 128 + c] = (_Float16)acc[r];
}

// ---------------------------------------------------------------------------
// edge_kernel, 512 threads (8 waves x 16 rows), dst-sorted edges (R2 structure).
//   A-frags of GEMM1 loaded global->regs in MFMA layout (no sA1 staging).
//   GEMM1 -> swish -> sT (LDS) -> GEMM2 -> he*C -> sM (f16) ->
//   column-threaded segmented run-reduction with PREFETCHED hv gather.
//   sMeta built in-kernel from eid (srcv/dstv/rij are L3-resident gathers).
// LDS: R0[0,16K): sW1 then sT rows 0-63; R1[16K,48K): sW2; R2[48K,64K): sT
//      rows 64-127; sM f16 [128][132] overlays [16K, 49K) in phase C. 64 KB.
// MFMA 16x16x32_f16 layouts (verified): A: m=lane&15, k=(lane>>4)*8+j;
//   D: row=(lane>>4)*4+r, col=lane&15.
// ---------------------------------------------------------------------------
__global__ __launch_bounds__(512, 4) void edge_kernel(
        const float* __restrict__ fij, const _Float16* __restrict__ hvh,
        const _Float16* __restrict__ W1img, const _Float16* __restrict__ W2img,
        const float* __restrict__ bf1, const float* __restrict__ bf2,
        const int* __restrict__ eids, const int* __restrict__ srcv,
        const int* __restrict__ dstv, const float* __restrict__ rij,
        float* __restrict__ agg) {
    __shared__ __align__(16) char smem[65536];
    __shared__ __align__(16) int4 sMeta[128];
    _Float16* sW1 = (_Float16*)smem;              // [128][64]   phase A
    _Float16* sW2 = (_Float16*)(smem + 16384);    // [128][128]  phases A-B
    _Float16* sT0 = (_Float16*)smem;              // sT rows 0-63
    _Float16* sT1 = (_Float16*)(smem + 49152);    // sT rows 64-127
    _Float16* sM  = (_Float16*)(smem + 16384);    // [128][132] f16, phase C

    const int tid = threadIdx.x;
    const int lane = tid & 63;
    const int wv = tid >> 6;          // 0..7 -> rows [wv*16, wv*16+16)
    const int l15 = lane & 15;
    const int q = lane >> 4;
    const int e0 = blockIdx.x * 128;

    // ---- early: this lane's A-frag row + direct global->reg fij loads ----
    const int arow = wv * 16 + l15;
    const int eid = eids[e0 + arow];
    const float* frow = fij + (long)eid * 50;
    // ks=0: k = q*8 + j (< 32, always valid); 8B-aligned float2 loads
    float2 p0 = *(const float2*)(frow + q * 8 + 0);
    float2 p1 = *(const float2*)(frow + q * 8 + 2);
    float2 p2 = *(const float2*)(frow + q * 8 + 4);
    float2 p3 = *(const float2*)(frow + q * 8 + 6);
    // ks=1: k = 32 + q*8 + j; pairs never straddle the k=50 cut (50 even)
    const int kb = 32 + q * 8;
    float2 z2 = make_float2(0.f, 0.f);
    float2 p4 = (kb + 1 < 50) ? *(const float2*)(frow + kb + 0) : z2;
    float2 p5 = (kb + 3 < 50) ? *(const float2*)(frow + kb + 2) : z2;
    float2 p6 = (kb + 5 < 50) ? *(const float2*)(frow + kb + 4) : z2;
    float2 p7 = (kb + 7 < 50) ? *(const float2*)(frow + kb + 6) : z2;
    f16x8 a0, a1;
    a0[0] = (_Float16)p0.x; a0[1] = (_Float16)p0.y;
    a0[2] = (_Float16)p1.x; a0[3] = (_Float16)p1.y;
    a0[4] = (_Float16)p2.x; a0[5] = (_Float16)p2.y;
    a0[6] = (_Float16)p3.x; a0[7] = (_Float16)p3.y;
    a1[0] = (_Float16)p4.x; a1[1] = (_Float16)p4.y;
    a1[2] = (_Float16)p5.x; a1[3] = (_Float16)p5.y;
    a1[4] = (_Float16)p6.x; a1[5] = (_Float16)p6.y;
    a1[6] = (_Float16)p7.x; a1[7] = (_Float16)p7.y;

    // ---- stage sMeta (gather by eid; srcv/dstv/rij L3-resident) + weights --
    if (tid < 128) {
        int e = eids[e0 + tid];
        sMeta[tid] = make_int4(e, srcv[e], dstv[e], __float_as_int(rij[e]));
    }
    {
        const float4* s1 = (const float4*)W1img;   // 1024 f4
        float4* d1 = (float4*)sW1;
        d1[tid] = s1[tid]; d1[tid + 512] = s1[tid + 512];
        const float4* s2 = (const float4*)W2img;   // 2048 f4
        float4* d2 = (float4*)sW2;
        for (int t = 0; t < 4; ++t) d2[tid + 512 * t] = s2[tid + 512 * t];
    }
    float b1v[8], b2v[8];
    for (int nb = 0; nb < 8; ++nb) {
        b1v[nb] = bf1[nb * 16 + l15];
        b2v[nb] = bf2[nb * 16 + l15];
    }
    __syncthreads();

    // ---- prefetch hv gather for the reduction (latency hides under GEMMs) -
    // reduction mapping: col-pair col2 = tid&63 -> cols {2*col2, 2*col2+1};
    // seg = tid>>6 (wave-uniform) -> rows [seg*16, seg*16+16).
    const int col2 = tid & 63;
    const int rseg0 = (tid >> 6) * 16;
    unsigned int pf[16];
    #pragma unroll
    for (int i = 0; i < 16; ++i) {
        long srcn = sMeta[rseg0 + i].y;            // wave-uniform LDS broadcast
        pf[i] = *(const unsigned int*)(hvh + srcn * 128 + col2 * 2);
    }

    // ---- GEMM1: [16 x 64] x [64 x 128] per wave, A from regs ----
    f32x4 acc[8];
    for (int nb = 0; nb < 8; ++nb) acc[nb] = (f32x4){0.f, 0.f, 0.f, 0.f};
    {
        f16x8 b[8];
        for (int nb = 0; nb < 8; ++nb) {
            int n = nb * 16 + l15;
            b[nb] = *(const f16x8*)&sW1[n * 64 + ((q ^ (n & 7)) << 3)];
        }
        for (int nb = 0; nb < 8; ++nb)
            acc[nb] = __builtin_amdgcn_mfma_f32_16x16x32_f16(a0, b[nb], acc[nb], 0, 0, 0);
        for (int nb = 0; nb < 8; ++nb) {
            int n = nb * 16 + l15;
            b[nb] = *(const f16x8*)&sW1[n * 64 + (((4 + q) ^ (n & 7)) << 3)];
        }
        for (int nb = 0; nb < 8; ++nb)
            acc[nb] = __builtin_amdgcn_mfma_f32_16x16x32_f16(a1, b[nb], acc[nb], 0, 0, 0);
    }
    __syncthreads();   // sW1 dead -> sT overlays R0 (+R2)

    // ---- epilogue1: t = swish(x1 + bf1) -> sT (swizzled) ----
    for (int nb = 0; nb < 8; ++nb)
        for (int r = 0; r < 4; ++r) {
            float x = acc[nb][r] + b1v[nb];
            float tt = x * fast_rcp(1.0f + __expf(-x));
            int row = wv * 16 + q * 4 + r;
            int col = nb * 16 + l15;
            _Float16* base = (row < 64) ? sT0 + row * 128 : sT1 + (row - 64) * 128;
            base[(((col >> 3) ^ (row & 7)) << 3) + (col & 7)] = (_Float16)tt;
        }
    __syncthreads();

    // ---- GEMM2: [16 x 128] x [128 x 128] per wave ----
    for (int nb = 0; nb < 8; ++nb) acc[nb] = (f32x4){0.f, 0.f, 0.f, 0.f};
    {
        const int row = wv * 16 + l15;
        const _Float16* abase = (row < 64) ? sT0 + row * 128 : sT1 + (row - 64) * 128;
        for (int ks = 0; ks < 4; ++ks) {
            int c = ks * 4 + q;
            f16x8 a = *(const f16x8*)&abase[(c ^ (row & 7)) << 3];
            for (int nb = 0; nb < 8; ++nb) {
                int n = nb * 16 + l15;
                f16x8 b = *(const f16x8*)&sW2[n * 128 + ((c ^ (n & 7)) << 3)];
                acc[nb] = __builtin_amdgcn_mfma_f32_16x16x32_f16(a, b, acc[nb], 0, 0, 0);
            }
        }
    }
    __syncthreads();   // sT, sW2 dead -> sM overlays [16K, 49K)

    // ---- epilogue2: he = (x2+bf2)*C -> sM f16, row stride 132 (bank-safe) --
    for (int r = 0; r < 4; ++r) {
        int row = wv * 16 + q * 4 + r;
        float rv = __int_as_float(sMeta[row].w);
        float Cr = (rv < 5.0f) ? 0.5f * (__cosf(0.6283185307179586f * rv) + 1.0f) : 0.0f;
        for (int nb = 0; nb < 8; ++nb) {
            int col = nb * 16 + l15;
            sM[row * 132 + col] = (_Float16)((acc[nb][r] + b2v[nb]) * Cr);
        }
    }
    __syncthreads();

    // ---- reduction: 8 segs x 16 rows x 64 col-pairs; hv from prefetch regs -
    {
        float run0 = 0.0f, run1 = 0.0f;
        int cur = sMeta[rseg0].z;
        #pragma unroll
        for (int i = 0; i < 16; ++i) {
            int r = rseg0 + i;
            int d = sMeta[r].z;                 // wave-uniform broadcast
            if (d != cur) {                     // wave-uniform branch
                atomicAdd(&agg[cur * 128 + col2 * 2], run0);
                atomicAdd(&agg[cur * 128 + col2 * 2 + 1], run1);
                run0 = 0.0f; run1 = 0.0f; cur = d;
            }
            union { unsigned int u; _Float16 h[2]; } hv2; hv2.u = pf[i];
            union { unsigned int u; _Float16 h[2]; } m2;
            m2.u = *(const unsigned int*)&sM[r * 132 + col2 * 2];
            run0 += (float)hv2.h[0] * (float)m2.h[0];
            run1 += (float)hv2.h[1] * (float)m2.h[1];
        }
        atomicAdd(&agg[cur * 128 + col2 * 2], run0);
        atomicAdd(&agg[cur * 128 + col2 * 2 + 1], run1);
    }
}

// ---------------------------------------------------------------------------
// out_kernel (fp32): out = swish(agg @ Wm1 + bm1) @ Wm2 + bm2, fused.
// ---------------------------------------------------------------------------
__global__ __launch_bounds__(256) void out_kernel(const float* __restrict__ agg,
                                                  const float* __restrict__ Wm1,
                                                  const float* __restrict__ bm1,
                                                  const float* __restrict__ Wm2,
                                                  const float* __restrict__ bm2,
                                                  float* __restrict__ out) {
    __shared__ float sAT[128 * 20];
    __shared__ float sTT[128 * 20];
    const int tid = threadIdx.x;
    const int row0 = blockIdx.x * 16;
    for (int t = 0; t < 8; ++t) {
        int flat = tid + 256 * t;
        int rr = flat >> 7, k = flat & 127;
        sAT[k * 20 + rr] = agg[(row0 + rr) * 128 + k];
    }
    __syncthreads();
    const int c = tid & 127, rh = tid >> 7;
    float acc[8] = {0, 0, 0, 0, 0, 0, 0, 0};
    for (int k = 0; k < 128; ++k) {
        float wval = Wm1[k * 128 + c];
        const float4 alo = *(const float4*)&sAT[k * 20 + rh * 8];
        const float4 ahi = *(const float4*)&sAT[k * 20 + rh * 8 + 4];
        acc[0] += alo.x * wval; acc[1] += alo.y * wval;
        acc[2] += alo.z * wval; acc[3] += alo.w * wval;
        acc[4] += ahi.x * wval; acc[5] += ahi.y * wval;
        acc[6] += ahi.z * wval; acc[7] += ahi.w * wval;
    }
    float bm1c = bm1[c];
    for (int r = 0; r < 8; ++r) {
        float x = acc[r] + bm1c;
        sTT[c * 20 + rh * 8 + r] = x * fast_rcp(1.0f + __expf(-x));
    }
    __syncthreads();
    float acc2[8] = {0, 0, 0, 0, 0, 0, 0, 0};
    for (int k = 0; k < 128; ++k) {
        float wval = Wm2[k * 128 + c];
        const float4 alo = *(const float4*)&sTT[k * 20 + rh * 8];
        const float4 ahi = *(const float4*)&sTT[k * 20 + rh * 8 + 4];
        acc2[0] += alo.x * wval; acc2[1] += alo.y * wval;
        acc2[2] += alo.z * wval; acc2[3] += alo.w * wval;
        acc2[4] += ahi.x * wval; acc2[5] += ahi.y * wval;
        acc2[6] += ahi.z * wval; acc2[7] += ahi.w * wval;
    }
    float bm2c = bm2[c];
    for (int r = 0; r < 8; ++r)
        out[(row0 + rh * 8 + r) * 128 + c] = acc2[r] + bm2c;
}

// ---------------------------------------------------------------------------
extern "C" void kernel_launch(void* const* d_in, const int* in_sizes, int n_in,
                              void* d_out, int out_size, void* d_ws, size_t ws_size,
                              hipStream_t stream) {
    const float* feat   = (const float*)d_in[0];
    const float* fij    = (const float*)d_in[1];
    const float* rij    = (const float*)d_in[2];
    const int*   srcv   = (const int*)d_in[3];
    const int*   dstv   = (const int*)d_in[4];
    const float* W_in2f = (const float*)d_in[5];
    const float* Wf1    = (const float*)d_in[6];
    const float* bf1    = (const float*)d_in[7];
    const float* Wf2    = (const float*)d_in[8];
    const float* bf2    = (const float*)d_in[9];
    const float* Wm1    = (const float*)d_in[10];
    const float* bm1    = (const float*)d_in[11];
    const float* Wm2    = (const float*)d_in[12];
    const float* bm2    = (const float*)d_in[13];
    float* out = (float*)d_out;

    char* ws = (char*)d_ws;
    float*    agg   = (float*)ws;                           // 25,600,000 B
    _Float16* hvh   = (_Float16*)(ws + 25600000);           // 12,800,000 B
    int*      eids  = (int*)(ws + 38400000);                //  6,400,000 B
    int*      cnt   = (int*)(ws + 64000000);                //    200,000 B
    int*      bsum  = (int*)(ws + 64200000);                //        256 B
    _Float16* W1img = (_Float16*)(ws + 64200704);           //     16,384 B
    _Float16* W2img = (_Float16*)(ws + 64217088);           //     32,768 B

    hipMemsetAsync(agg, 0, (size_t)N_NODES * 128 * sizeof(float), stream);
    hipMemsetAsync(cnt, 0, (size_t)N_NODES * sizeof(int), stream);
    prep_weights<<<64, 256, 0, stream>>>(Wf1, Wf2, W1img, W2img);
    hv_kernel<<<3125, 256, 0, stream>>>(feat, W_in2f, hvh);
    hist_kernel<<<(N_EDGES + 255) / 256, 256, 0, stream>>>(dstv, cnt);
    scan_reduce<<<49, 1024, 0, stream>>>(cnt, bsum);
    scan_top<<<1, 64, 0, stream>>>(bsum);
    scan_apply<<<49, 1024, 0, stream>>>(cnt, bsum);
    scatter_kernel<<<(N_EDGES + 255) / 256, 256, 0, stream>>>(dstv, cnt, eids);
    edge_kernel<<<12500, 512, 0, stream>>>(fij, hvh, W1img, W2img, bf1, bf2,
                                           eids, srcv, dstv, rij, agg);
    out_kernel<<<3125, 256, 0, stream>>>(agg, Wm1, bm1, Wm2, bm2, out);
}

// Round 6
// 871.726 us; speedup vs baseline: 1.8356x; 1.1259x over previous
//
#include <hip/hip_runtime.h>

#define N_NODES 50000
#define N_EDGES 1600000

typedef _Float16 f16x8 __attribute__((ext_vector_type(8)));
typedef float f32x4 __attribute__((ext_vector_type(4)));

__device__ __forceinline__ float fast_rcp(float v) {
#if __has_builtin(__builtin_amdgcn_rcpf)
    return __builtin_amdgcn_rcpf(v);
#else
    return __frcp_rn(v);
#endif
}

// ---------------------------------------------------------------------------
// prep_weights: f16 weight images, transposed ([n][k]) and 16B-chunk
// XOR-swizzled (chunk' = chunk ^ (n&7)).
// W1img: [128][64] (Wf1 50x128, K zero-padded to 64).
// W2img/Wi2fimg/Wm1img/Wm2img: [128][128] from Wf2/W_in2f/Wm1/Wm2.
// ---------------------------------------------------------------------------
__global__ void prep_weights(const float* __restrict__ Wf1,
                             const float* __restrict__ Wf2,
                             const float* __restrict__ W_in2f,
                             const float* __restrict__ Wm1,
                             const float* __restrict__ Wm2,
                             _Float16* __restrict__ W1img,
                             _Float16* __restrict__ W2img,
                             _Float16* __restrict__ Wi2fimg,
                             _Float16* __restrict__ Wm1img,
                             _Float16* __restrict__ Wm2img) {
    int i = blockIdx.x * 256 + threadIdx.x;
    if (i < 8192) {
        int n = i >> 6, k = i & 63;
        float v = (k < 50) ? Wf1[k * 128 + n] : 0.0f;
        W1img[n * 64 + (((k >> 3) ^ (n & 7)) << 3) + (k & 7)] = (_Float16)v;
    }
    if (i < 16384) {
        int n = i >> 7, k = i & 127;
        int off = n * 128 + (((k >> 3) ^ (n & 7)) << 3) + (k & 7);
        int src = k * 128 + n;
        W2img[off]   = (_Float16)Wf2[src];
        Wi2fimg[off] = (_Float16)W_in2f[src];
        Wm1img[off]  = (_Float16)Wm1[src];
        Wm2img[off]  = (_Float16)Wm2[src];
    }
}

// ---------------------------------------------------------------------------
// fused_hv_hist: blocks [0,391) do hv = feat @ W_in2f via MFMA (f16 in,
// fp32 acc, f16 store); blocks [391, 391+3125) do the dst histogram.
// hv tile: 128 rows/block, 8 waves x 16 rows, B-frags from global Wi2fimg
// (32KB, L1/L2-hot). Independent work -> one launch, overlapped execution.
// ---------------------------------------------------------------------------
__global__ __launch_bounds__(512) void fused_hv_hist(
        const float* __restrict__ feat, const _Float16* __restrict__ Wi2fimg,
        _Float16* __restrict__ hvh,
        const int* __restrict__ dstv, int* __restrict__ cnt) {
    const int b = blockIdx.x;
    const int tid = threadIdx.x;
    if (b < 391) {
        const int lane = tid & 63, wv = tid >> 6;
        const int l15 = lane & 15, q = lane >> 4;
        const int row0 = b * 128;
        int ar = row0 + wv * 16 + l15;
        if (ar > N_NODES - 1) ar = N_NODES - 1;
        const float* arow = feat + (long)ar * 128;
        f16x8 a[4];
        #pragma unroll
        for (int ks = 0; ks < 4; ++ks) {
            const float* p = arow + ks * 32 + q * 8;
            float2 u0 = *(const float2*)(p + 0);
            float2 u1 = *(const float2*)(p + 2);
            float2 u2 = *(const float2*)(p + 4);
            float2 u3 = *(const float2*)(p + 6);
            a[ks][0] = (_Float16)u0.x; a[ks][1] = (_Float16)u0.y;
            a[ks][2] = (_Float16)u1.x; a[ks][3] = (_Float16)u1.y;
            a[ks][4] = (_Float16)u2.x; a[ks][5] = (_Float16)u2.y;
            a[ks][6] = (_Float16)u3.x; a[ks][7] = (_Float16)u3.y;
        }
        f32x4 acc[8];
        for (int nb = 0; nb < 8; ++nb) acc[nb] = (f32x4){0.f, 0.f, 0.f, 0.f};
        #pragma unroll
        for (int ks = 0; ks < 4; ++ks) {
            int c = ks * 4 + q;
            #pragma unroll
            for (int nb = 0; nb < 8; ++nb) {
                int n = nb * 16 + l15;
                f16x8 bf = *(const f16x8*)&Wi2fimg[n * 128 + ((c ^ (n & 7)) << 3)];
                acc[nb] = __builtin_amdgcn_mfma_f32_16x16x32_f16(a[ks], bf, acc[nb], 0, 0, 0);
            }
        }
        #pragma unroll
        for (int nb = 0; nb < 8; ++nb)
            #pragma unroll
            for (int r = 0; r < 4; ++r) {
                int orow = row0 + wv * 16 + q * 4 + r;
                if (orow < N_NODES)
                    hvh[(long)orow * 128 + nb * 16 + l15] = (_Float16)acc[nb][r];
            }
    } else {
        int e = (b - 391) * 512 + tid;
        if (e < N_EDGES) atomicAdd(&cnt[dstv[e]], 1);
    }
}

// ---------------------------------------------------------------------------
// Counting sort by dst: hist (fused above) -> 3-kernel shuffle scan -> scatter.
// ---------------------------------------------------------------------------
__global__ __launch_bounds__(1024) void scan_reduce(const int* __restrict__ cnt,
                                                    int* __restrict__ bsum) {
    __shared__ int ws[16];
    int tid = threadIdx.x, lane = tid & 63;
    int i = blockIdx.x * 1024 + tid;
    int x = (i < N_NODES) ? cnt[i] : 0;
    for (int o = 32; o > 0; o >>= 1) x += __shfl_down(x, o);
    if (lane == 0) ws[tid >> 6] = x;
    __syncthreads();
    if (tid == 0) {
        int s = 0;
        for (int w = 0; w < 16; ++w) s += ws[w];
        bsum[blockIdx.x] = s;
    }
}

__global__ void scan_top(int* __restrict__ bsum) {   // 49 block sums, serial
    if (threadIdx.x == 0) {
        int s = 0;
        for (int b = 0; b < 49; ++b) { int v = bsum[b]; bsum[b] = s; s += v; }
    }
}

__global__ __launch_bounds__(1024) void scan_apply(int* __restrict__ cnt,
                                                   const int* __restrict__ bsum) {
    __shared__ int ws[16], wo[16];
    int tid = threadIdx.x, lane = tid & 63, wid = tid >> 6;
    int i = blockIdx.x * 1024 + tid;
    int x = (i < N_NODES) ? cnt[i] : 0;
    int incl = x;
    for (int o = 1; o < 64; o <<= 1) {
        int y = __shfl_up(incl, o);
        if (lane >= o) incl += y;
    }
    if (lane == 63) ws[wid] = incl;
    __syncthreads();
    if (tid == 0) {
        int s = 0;
        for (int w = 0; w < 16; ++w) { wo[w] = s; s += ws[w]; }
    }
    __syncthreads();
    if (i < N_NODES) cnt[i] = bsum[blockIdx.x] + wo[wid] + incl - x;  // exclusive
}

__global__ void scatter_kernel(const int* __restrict__ dstv,
                               const int* __restrict__ srcv,
                               const float* __restrict__ rij,
                               int* __restrict__ cursor,
                               int4* __restrict__ meta) {
    int e = blockIdx.x * 256 + threadIdx.x;
    if (e < N_EDGES) {
        int d = dstv[e];
        int pos = atomicAdd(&cursor[d], 1);
        meta[pos] = make_int4(e, srcv[e], d, __float_as_int(rij[e]));
    }
}

// ---------------------------------------------------------------------------
// edge_kernel, 512 threads (8 waves x 16 rows), dst-sorted edges (R2 struct).
//   A-frags of GEMM1 loaded global->regs in MFMA layout (no sA1 staging).
//   GEMM1 -> swish -> sT (LDS) -> GEMM2 -> he*C -> sM (f16) ->
//   column-threaded segmented run-reduction with PREFETCHED hv gather
//   (16 dword loads issued right after sMeta; latency hides under GEMMs).
// LDS: R0[0,16K): sW1 then sT rows 0-63; R1[16K,48K): sW2; R2[48K,64K): sT
//      rows 64-127; sM f16 [128][132] overlays [16K, 49K) in phase C. 64 KB.
// MFMA 16x16x32_f16 layouts (verified): A: m=lane&15, k=(lane>>4)*8+j;
//   D: row=(lane>>4)*4+r, col=lane&15.
// ---------------------------------------------------------------------------
__global__ __launch_bounds__(512, 4) void edge_kernel(
        const float* __restrict__ fij, const _Float16* __restrict__ hvh,
        const _Float16* __restrict__ W1img, const _Float16* __restrict__ W2img,
        const float* __restrict__ bf1, const float* __restrict__ bf2,
        const int4* __restrict__ meta, float* __restrict__ agg) {
    __shared__ __align__(16) char smem[65536];
    __shared__ __align__(16) int4 sMeta[128];
    _Float16* sW1 = (_Float16*)smem;              // [128][64]   phase A
    _Float16* sW2 = (_Float16*)(smem + 16384);    // [128][128]  phases A-B
    _Float16* sT0 = (_Float16*)smem;              // sT rows 0-63
    _Float16* sT1 = (_Float16*)(smem + 49152);    // sT rows 64-127
    _Float16* sM  = (_Float16*)(smem + 16384);    // [128][132] f16, phase C

    const int tid = threadIdx.x;
    const int lane = tid & 63;
    const int wv = tid >> 6;          // 0..7 -> rows [wv*16, wv*16+16)
    const int l15 = lane & 15;
    const int q = lane >> 4;
    const int e0 = blockIdx.x * 128;

    // ---- early: this lane's A-frag row + direct global->reg fij loads ----
    const int arow = wv * 16 + l15;
    const int eid = meta[e0 + arow].x;
    const float* frow = fij + (long)eid * 50;
    // ks=0: k = q*8 + j (< 32, always valid); 8B-aligned float2 loads
    float2 p0 = *(const float2*)(frow + q * 8 + 0);
    float2 p1 = *(const float2*)(frow + q * 8 + 2);
    float2 p2 = *(const float2*)(frow + q * 8 + 4);
    float2 p3 = *(const float2*)(frow + q * 8 + 6);
    // ks=1: k = 32 + q*8 + j; pairs never straddle the k=50 cut (50 even)
    const int kb = 32 + q * 8;
    float2 z2 = make_float2(0.f, 0.f);
    float2 p4 = (kb + 1 < 50) ? *(const float2*)(frow + kb + 0) : z2;
    float2 p5 = (kb + 3 < 50) ? *(const float2*)(frow + kb + 2) : z2;
    float2 p6 = (kb + 5 < 50) ? *(const float2*)(frow + kb + 4) : z2;
    float2 p7 = (kb + 7 < 50) ? *(const float2*)(frow + kb + 6) : z2;
    f16x8 a0, a1;
    a0[0] = (_Float16)p0.x; a0[1] = (_Float16)p0.y;
    a0[2] = (_Float16)p1.x; a0[3] = (_Float16)p1.y;
    a0[4] = (_Float16)p2.x; a0[5] = (_Float16)p2.y;
    a0[6] = (_Float16)p3.x; a0[7] = (_Float16)p3.y;
    a1[0] = (_Float16)p4.x; a1[1] = (_Float16)p4.y;
    a1[2] = (_Float16)p5.x; a1[3] = (_Float16)p5.y;
    a1[4] = (_Float16)p6.x; a1[5] = (_Float16)p6.y;
    a1[6] = (_Float16)p7.x; a1[7] = (_Float16)p7.y;

    // ---- stage sMeta + weight images ----
    if (tid < 128) sMeta[tid] = meta[e0 + tid];
    {
        const float4* s1 = (const float4*)W1img;   // 1024 f4
        float4* d1 = (float4*)sW1;
        d1[tid] = s1[tid]; d1[tid + 512] = s1[tid + 512];
        const float4* s2 = (const float4*)W2img;   // 2048 f4
        float4* d2 = (float4*)sW2;
        for (int t = 0; t < 4; ++t) d2[tid + 512 * t] = s2[tid + 512 * t];
    }
    float b1v[8], b2v[8];
    for (int nb = 0; nb < 8; ++nb) {
        b1v[nb] = bf1[nb * 16 + l15];
        b2v[nb] = bf2[nb * 16 + l15];
    }
    __syncthreads();

    // ---- prefetch hv gather for the reduction (latency hides under GEMMs) -
    const int col2 = tid & 63;
    const int rseg0 = (tid >> 6) * 16;
    unsigned int pf[16];
    #pragma unroll
    for (int i = 0; i < 16; ++i) {
        long srcn = sMeta[rseg0 + i].y;            // wave-uniform LDS broadcast
        pf[i] = *(const unsigned int*)(hvh + srcn * 128 + col2 * 2);
    }

    // ---- GEMM1: [16 x 64] x [64 x 128] per wave, A from regs ----
    f32x4 acc[8];
    for (int nb = 0; nb < 8; ++nb) acc[nb] = (f32x4){0.f, 0.f, 0.f, 0.f};
    {
        f16x8 b[8];
        for (int nb = 0; nb < 8; ++nb) {
            int n = nb * 16 + l15;
            b[nb] = *(const f16x8*)&sW1[n * 64 + ((q ^ (n & 7)) << 3)];
        }
        for (int nb = 0; nb < 8; ++nb)
            acc[nb] = __builtin_amdgcn_mfma_f32_16x16x32_f16(a0, b[nb], acc[nb], 0, 0, 0);
        for (int nb = 0; nb < 8; ++nb) {
            int n = nb * 16 + l15;
            b[nb] = *(const f16x8*)&sW1[n * 64 + (((4 + q) ^ (n & 7)) << 3)];
        }
        for (int nb = 0; nb < 8; ++nb)
            acc[nb] = __builtin_amdgcn_mfma_f32_16x16x32_f16(a1, b[nb], acc[nb], 0, 0, 0);
    }
    __syncthreads();   // sW1 dead -> sT overlays R0 (+R2)

    // ---- epilogue1: t = swish(x1 + bf1) -> sT (swizzled) ----
    for (int nb = 0; nb < 8; ++nb)
        for (int r = 0; r < 4; ++r) {
            float x = acc[nb][r] + b1v[nb];
            float tt = x * fast_rcp(1.0f + __expf(-x));
            int row = wv * 16 + q * 4 + r;
            int col = nb * 16 + l15;
            _Float16* base = (row < 64) ? sT0 + row * 128 : sT1 + (row - 64) * 128;
            base[(((col >> 3) ^ (row & 7)) << 3) + (col & 7)] = (_Float16)tt;
        }
    __syncthreads();

    // ---- GEMM2: [16 x 128] x [128 x 128] per wave ----
    for (int nb = 0; nb < 8; ++nb) acc[nb] = (f32x4){0.f, 0.f, 0.f, 0.f};
    {
        const int row = wv * 16 + l15;
        const _Float16* abase = (row < 64) ? sT0 + row * 128 : sT1 + (row - 64) * 128;
        for (int ks = 0; ks < 4; ++ks) {
            int c = ks * 4 + q;
            f16x8 a = *(const f16x8*)&abase[(c ^ (row & 7)) << 3];
            for (int nb = 0; nb < 8; ++nb) {
                int n = nb * 16 + l15;
                f16x8 b = *(const f16x8*)&sW2[n * 128 + ((c ^ (n & 7)) << 3)];
                acc[nb] = __builtin_amdgcn_mfma_f32_16x16x32_f16(a, b, acc[nb], 0, 0, 0);
            }
        }
    }
    __syncthreads();   // sT, sW2 dead -> sM overlays [16K, 49K)

    // ---- epilogue2: he = (x2+bf2)*C -> sM f16, row stride 132 (bank-safe) --
    for (int r = 0; r < 4; ++r) {
        int row = wv * 16 + q * 4 + r;
        float rv = __int_as_float(sMeta[row].w);
        float Cr = (rv < 5.0f) ? 0.5f * (__cosf(0.6283185307179586f * rv) + 1.0f) : 0.0f;
        for (int nb = 0; nb < 8; ++nb) {
            int col = nb * 16 + l15;
            sM[row * 132 + col] = (_Float16)((acc[nb][r] + b2v[nb]) * Cr);
        }
    }
    __syncthreads();

    // ---- reduction: 8 segs x 16 rows x 64 col-pairs; hv from prefetch regs -
    {
        float run0 = 0.0f, run1 = 0.0f;
        int cur = sMeta[rseg0].z;
        #pragma unroll
        for (int i = 0; i < 16; ++i) {
            int r = rseg0 + i;
            int d = sMeta[r].z;                 // wave-uniform broadcast
            if (d != cur) {                     // wave-uniform branch
                atomicAdd(&agg[cur * 128 + col2 * 2], run0);
                atomicAdd(&agg[cur * 128 + col2 * 2 + 1], run1);
                run0 = 0.0f; run1 = 0.0f; cur = d;
            }
            union { unsigned int u; _Float16 h[2]; } hv2; hv2.u = pf[i];
            union { unsigned int u; _Float16 h[2]; } m2;
            m2.u = *(const unsigned int*)&sM[r * 132 + col2 * 2];
            run0 += (float)hv2.h[0] * (float)m2.h[0];
            run1 += (float)hv2.h[1] * (float)m2.h[1];
        }
        atomicAdd(&agg[cur * 128 + col2 * 2], run0);
        atomicAdd(&agg[cur * 128 + col2 * 2 + 1], run1);
    }
}

// ---------------------------------------------------------------------------
// out_kernel (MFMA): out = swish(agg @ Wm1 + bm1) @ Wm2 + bm2.
// 128 rows/block, 8 waves x 16 rows; agg fp32 -> f16 A-frags; B-frags from
// global Wm1img/Wm2img (L2-hot); sT intermediate in LDS (32KB, swizzled).
// ---------------------------------------------------------------------------
__global__ __launch_bounds__(512) void out_kernel(const float* __restrict__ agg,
                                                  const _Float16* __restrict__ Wm1img,
                                                  const float* __restrict__ bm1,
                                                  const _Float16* __restrict__ Wm2img,
                                                  const float* __restrict__ bm2,
                                                  float* __restrict__ out) {
    __shared__ __align__(16) _Float16 sT[128 * 128];
    const int tid = threadIdx.x, lane = tid & 63, wv = tid >> 6;
    const int l15 = lane & 15, q = lane >> 4;
    const int row0 = blockIdx.x * 128;
    int ar = row0 + wv * 16 + l15;
    if (ar > N_NODES - 1) ar = N_NODES - 1;
    const float* arow = agg + (long)ar * 128;
    f16x8 a[4];
    #pragma unroll
    for (int ks = 0; ks < 4; ++ks) {
        const float* p = arow + ks * 32 + q * 8;
        float2 u0 = *(const float2*)(p + 0);
        float2 u1 = *(const float2*)(p + 2);
        float2 u2 = *(const float2*)(p + 4);
        float2 u3 = *(const float2*)(p + 6);
        a[ks][0] = (_Float16)u0.x; a[ks][1] = (_Float16)u0.y;
        a[ks][2] = (_Float16)u1.x; a[ks][3] = (_Float16)u1.y;
        a[ks][4] = (_Float16)u2.x; a[ks][5] = (_Float16)u2.y;
        a[ks][6] = (_Float16)u3.x; a[ks][7] = (_Float16)u3.y;
    }
    float b1v[8], b2v[8];
    for (int nb = 0; nb < 8; ++nb) {
        b1v[nb] = bm1[nb * 16 + l15];
        b2v[nb] = bm2[nb * 16 + l15];
    }
    f32x4 acc[8];
    for (int nb = 0; nb < 8; ++nb) acc[nb] = (f32x4){0.f, 0.f, 0.f, 0.f};
    #pragma unroll
    for (int ks = 0; ks < 4; ++ks) {
        int c = ks * 4 + q;
        #pragma unroll
        for (int nb = 0; nb < 8; ++nb) {
            int n = nb * 16 + l15;
            f16x8 bf = *(const f16x8*)&Wm1img[n * 128 + ((c ^ (n & 7)) << 3)];
            acc[nb] = __builtin_amdgcn_mfma_f32_16x16x32_f16(a[ks], bf, acc[nb], 0, 0, 0);
        }
    }
    // swish -> sT (swizzled, same scheme as edge)
    #pragma unroll
    for (int nb = 0; nb < 8; ++nb)
        #pragma unroll
        for (int r = 0; r < 4; ++r) {
            float x = acc[nb][r] + b1v[nb];
            float tt = x * fast_rcp(1.0f + __expf(-x));
            int row = wv * 16 + q * 4 + r;
            int col = nb * 16 + l15;
            sT[row * 128 + (((col >> 3) ^ (row & 7)) << 3) + (col & 7)] = (_Float16)tt;
        }
    __syncthreads();
    for (int nb = 0; nb < 8; ++nb) acc[nb] = (f32x4){0.f, 0.f, 0.f, 0.f};
    {
        const int rowA = wv * 16 + l15;
        const _Float16* abase = &sT[rowA * 128];
        #pragma unroll
        for (int ks = 0; ks < 4; ++ks) {
            int c = ks * 4 + q;
            f16x8 a2 = *(const f16x8*)&abase[(c ^ (rowA & 7)) << 3];
            #pragma unroll
            for (int nb = 0; nb < 8; ++nb) {
                int n = nb * 16 + l15;
                f16x8 bf = *(const f16x8*)&Wm2img[n * 128 + ((c ^ (n & 7)) << 3)];
                acc[nb] = __builtin_amdgcn_mfma_f32_16x16x32_f16(a2, bf, acc[nb], 0, 0, 0);
            }
        }
    }
    #pragma unroll
    for (int nb = 0; nb < 8; ++nb)
        #pragma unroll
        for (int r = 0; r < 4; ++r) {
            int orow = row0 + wv * 16 + q * 4 + r;
            if (orow < N_NODES)
                out[(long)orow * 128 + nb * 16 + l15] = acc[nb][r] + b2v[nb];
        }
}

// ---------------------------------------------------------------------------
extern "C" void kernel_launch(void* const* d_in, const int* in_sizes, int n_in,
                              void* d_out, int out_size, void* d_ws, size_t ws_size,
                              hipStream_t stream) {
    const float* feat   = (const float*)d_in[0];
    const float* fij    = (const float*)d_in[1];
    const float* rij    = (const float*)d_in[2];
    const int*   srcv   = (const int*)d_in[3];
    const int*   dstv   = (const int*)d_in[4];
    const float* W_in2f = (const float*)d_in[5];
    const float* Wf1    = (const float*)d_in[6];
    const float* bf1    = (const float*)d_in[7];
    const float* Wf2    = (const float*)d_in[8];
    const float* bf2    = (const float*)d_in[9];
    const float* Wm1    = (const float*)d_in[10];
    const float* bm1    = (const float*)d_in[11];
    const float* Wm2    = (const float*)d_in[12];
    const float* bm2    = (const float*)d_in[13];
    float* out = (float*)d_out;

    char* ws = (char*)d_ws;
    float*    agg     = (float*)ws;                         // 25,600,000 B
    _Float16* hvh     = (_Float16*)(ws + 25600000);         // 12,800,000 B
    int4*     meta    = (int4*)(ws + 38400000);             // 25,600,000 B
    int*      cnt     = (int*)(ws + 64000000);              //    200,000 B
    int*      bsum    = (int*)(ws + 64200000);              //        256 B
    _Float16* W1img   = (_Float16*)(ws + 64200704);         //     16,384 B
    _Float16* W2img   = (_Float16*)(ws + 64217088);         //     32,768 B
    _Float16* Wi2fimg = (_Float16*)(ws + 64249856);         //     32,768 B
    _Float16* Wm1img  = (_Float16*)(ws + 64282624);         //     32,768 B
    _Float16* Wm2img  = (_Float16*)(ws + 64315392);         //     32,768 B  (end 64,348,160 < 64 MiB)

    hipMemsetAsync(agg, 0, (size_t)N_NODES * 128 * sizeof(float), stream);
    hipMemsetAsync(cnt, 0, (size_t)N_NODES * sizeof(int), stream);
    prep_weights<<<64, 256, 0, stream>>>(Wf1, Wf2, W_in2f, Wm1, Wm2,
                                         W1img, W2img, Wi2fimg, Wm1img, Wm2img);
    fused_hv_hist<<<391 + 3125, 512, 0, stream>>>(feat, Wi2fimg, hvh, dstv, cnt);
    scan_reduce<<<49, 1024, 0, stream>>>(cnt, bsum);
    scan_top<<<1, 64, 0, stream>>>(bsum);
    scan_apply<<<49, 1024, 0, stream>>>(cnt, bsum);
    scatter_kernel<<<(N_EDGES + 255) / 256, 256, 0, stream>>>(dstv, srcv, rij, cnt, meta);
    edge_kernel<<<12500, 512, 0, stream>>>(fij, hvh, W1img, W2img, bf1, bf2, meta, agg);
    out_kernel<<<391, 512, 0, stream>>>(agg, Wm1img, bm1, Wm2img, bm2, out);
}